// Round 8
// baseline (264.560 us; speedup 1.0000x reference)
//
#include <hip/hip_runtime.h>
#include <hip/hip_bf16.h>

#define T_DIM 2048
#define N_DIM 256
#define K_DIM 256
#define C_DIM 40
#define CHUNK 32
#define NCHUNK 64            // T_DIM / CHUNK
#define NTILES (T_DIM * N_DIM / 16)   // 32768 M-tiles of 16 rows

#define LOG2E_F 1.44269504088896340736f
#define LN2_F   0.69314718055994530942f
#define NEGBIG  (-1.0e30f)

typedef short bf16x8 __attribute__((ext_vector_type(8)));
typedef float f32x4  __attribute__((ext_vector_type(4)));

__device__ __forceinline__ float fexp2(float x) { return exp2f(x); }
__device__ __forceinline__ float flog2(float x) { return log2f(x); }
__device__ __forceinline__ float frcp(float x) { return __frcp_rn(x); }

// two fp32 -> one u32 of two bf16 (compiler emits v_cvt_pk_bf16_f32; m240:
// scalar casts beat hand-written packs). memcpy not bit_cast:
// __hip_bfloat162 is not trivially copyable on this ROCm.
__device__ __forceinline__ unsigned int pk2(float a, float b)
{
    __hip_bfloat162 h = __float22bfloat162_rn(make_float2(a, b));
    unsigned int r;
    __builtin_memcpy(&r, &h, sizeof(r));
    return r;
}

__device__ __forceinline__ uint4 pack8u(float4 lo, float4 hi)
{
    uint4 t;
    t.x = pk2(lo.x, lo.y);
    t.y = pk2(lo.z, lo.w);
    t.z = pk2(hi.x, hi.y);
    t.w = pk2(hi.z, hi.w);
    return t;
}

__device__ __forceinline__ bf16x8 as_bf16x8(uint4 u)
{
    bf16x8 r;
    __builtin_memcpy(&r, &u, sizeof(r));
    return r;
}

__device__ __forceinline__ float tanh5(float v)
{
    const float e = fexp2(fabsf(v) * (2.0f * LOG2E_F)); // e^(2|v|)
    const float t = 1.0f - 2.0f * frcp(e + 1.0f);       // tanh(|v|)
    return 5.0f * copysignf(t, v);
}

// ---------------------------------------------------------------------------
// K1: y[row][c] = 5*tanh(dot(x[row], W[c]) + b[c])  via bf16 MFMA.
// W pre-packed per block into LDS as ready B-fragments (conflict-free
// ds_read_b128). K-PERMUTED fragment mapping: lane(lr,kg) takes x-cols
// {ks*32+kg*4..+3} u {ks*32+16+kg*4..+3}, so each wave load instruction
// covers 16 rows x 64 CONTIGUOUS bytes = full 32B sectors (the previous
// kg*8-mapping made lo/hi each request the same 64 sectors half-used ->
// 2x sector-request rate; suspected K1 cap at ~200us). W is permuted
// identically, so the dot product is unchanged.
// ---------------------------------------------------------------------------
__global__ __launch_bounds__(256, 4) void k1_gemm_tanh(
    const float* __restrict__ x, const float* __restrict__ W,
    const float* __restrict__ b, float* __restrict__ y)
{
    __shared__ __align__(16) uint4 wlds[24 * 64];   // 24.5 KB: frag=(ks*3+nt)
    __shared__ float blds[48];

    const int tid = threadIdx.x;

    // ---- cooperative W->fragment build (once per block), k-permuted ----
#pragma unroll
    for (int p = 0; p < 6; ++p) {
        const int f    = p * 256 + tid;   // 0..1535 lane-fragments
        const int l    = f & 63;
        const int frag = f >> 6;          // 0..23
        const int nt   = frag % 3;
        const int ks   = frag / 3;
        const int col  = nt * 16 + (l & 15);
        const int kg   = l >> 4;
        float4 lo = make_float4(0, 0, 0, 0), hi = lo;
        if (col < C_DIM) {
            lo = *(const float4*)(W + (size_t)col * K_DIM + ks * 32 + kg * 4);
            hi = *(const float4*)(W + (size_t)col * K_DIM + ks * 32 + 16 + kg * 4);
        }
        wlds[frag * 64 + l] = pack8u(lo, hi);
    }
    if (tid < 48) blds[tid] = (tid < C_DIM) ? b[tid] : 0.0f;
    __syncthreads();

    const int wave = tid >> 6;
    const int lane = tid & 63;
    const int lr   = lane & 15;   // A-row / B-col / D-col selector
    const int kg   = lane >> 4;   // k-group 0..3

    const float bc0 = blds[lr];
    const float bc1 = blds[16 + lr];
    const float bc2 = blds[32 + lr];

    const int wid = blockIdx.x * 4 + wave;          // 0..4095, all resident

#pragma unroll 1
    for (int tile = wid; tile < NTILES; tile += 4096) {
        // float4-granular base: row (tile*16+lr), col kg*4
        const float4* __restrict__ xp4 =
            (const float4*)(x + ((size_t)tile * 16 + lr) * K_DIM) + kg;

        f32x4 af0 = {bc0, bc0, bc0, bc0};
        f32x4 af1 = {bc1, bc1, bc1, bc1};
        f32x4 af2 = {bc2, bc2, bc2, bc2};

#pragma unroll
        for (int ks = 0; ks < 8; ++ks) {
            const float4 lo = xp4[ks * 8];       // x-cols ks*32 + kg*4 ..+3
            const float4 hi = xp4[ks * 8 + 4];   // x-cols ks*32+16+kg*4 ..+3
            const bf16x8 a = as_bf16x8(pack8u(lo, hi));
            const bf16x8 w0 = *(const bf16x8*)&wlds[(ks * 3 + 0) * 64 + lane];
            const bf16x8 w1 = *(const bf16x8*)&wlds[(ks * 3 + 1) * 64 + lane];
            const bf16x8 w2 = *(const bf16x8*)&wlds[(ks * 3 + 2) * 64 + lane];
            af0 = __builtin_amdgcn_mfma_f32_16x16x32_bf16(a, w0, af0, 0, 0, 0);
            af1 = __builtin_amdgcn_mfma_f32_16x16x32_bf16(a, w1, af1, 0, 0, 0);
            af2 = __builtin_amdgcn_mfma_f32_16x16x32_bf16(a, w2, af2, 0, 0, 0);
        }

        // epilogue: D[row][col], row = kg*4+r, col = nt*16+lr
        float* __restrict__ yrow = y + ((size_t)tile * 16 + kg * 4) * C_DIM;
#pragma unroll
        for (int r = 0; r < 4; ++r) {
            yrow[r * C_DIM + lr]      = tanh5(af0[r]);
            yrow[r * C_DIM + 16 + lr] = tanh5(af1[r]);
            if (lr < 8)
                yrow[r * C_DIM + 32 + lr] = tanh5(af2[r]);
        }
    }
}

// ---------------------------------------------------------------------------
// K2: per (chain n, chunk g) propagate the 8x8 log-semiring matrix through
// 32 steps. 8 lanes per task; lane c holds column M[:,c] -> inner loop is
// fully lane-local. Base-2 domain (scores pre-scaled by log2(e)).
// ---------------------------------------------------------------------------
__global__ __launch_bounds__(256) void k2_chunks(
    const float* __restrict__ y, float* __restrict__ cmat)
{
    const int tid  = threadIdx.x;
    const int wave = tid >> 6;
    const int lane = tid & 63;
    const int task = lane >> 3;   // 8 tasks per wave
    const int c    = lane & 7;    // column owned by this lane
    const int g    = blockIdx.x & (NCHUNK - 1);
    const int n    = ((blockIdx.x >> 6) << 5) + (wave << 3) + task;

    float col[8];
#pragma unroll
    for (int j = 0; j < 8; ++j) col[j] = (j == c) ? 0.0f : NEGBIG;

    const float* __restrict__ yp =
        y + ((size_t)(g * CHUNK) * N_DIM + (size_t)n) * C_DIM;

#pragma unroll 1
    for (int s = 0; s < CHUNK; ++s) {
        float sc[C_DIM];
        const float4* p4 = (const float4*)yp;
#pragma unroll
        for (int q = 0; q < 10; ++q) {
            const float4 v = p4[q];
            sc[4 * q + 0] = v.x * LOG2E_F;
            sc[4 * q + 1] = v.y * LOG2E_F;
            sc[4 * q + 2] = v.z * LOG2E_F;
            sc[4 * q + 3] = v.w * LOG2E_F;
        }
        float nc[8];
#pragma unroll
        for (int d = 0; d < 4; ++d) {          // dense rows: lse over 8
            float tv[8];
#pragma unroll
            for (int j = 0; j < 8; ++j) tv[j] = sc[d * 8 + j] + col[j];
            float m = tv[0];
#pragma unroll
            for (int j = 1; j < 8; ++j) m = fmaxf(m, tv[j]);
            float ss = 0.0f;
#pragma unroll
            for (int j = 0; j < 8; ++j) ss += fexp2(tv[j] - m);
            nc[d] = m + flog2(ss);
        }
#pragma unroll
        for (int i = 0; i < 4; ++i) {          // sparse rows: logaddexp of 2
            const float a  = sc[32 + i] + col[i];
            const float bb = sc[36 + i] + col[i + 4];
            const float m  = fmaxf(a, bb);
            const float ss = fexp2(a - m) + fexp2(bb - m);
            nc[4 + i] = m + flog2(ss);
        }
#pragma unroll
        for (int j = 0; j < 8; ++j) col[j] = nc[j];
        yp += (size_t)N_DIM * C_DIM;
    }
    // store M[j][c] at cmat[((g*8 + c)*N_DIM + n)*8 + j]  (contig 8 per lane)
    float* __restrict__ op = cmat + (((size_t)g * 8 + c) * N_DIM + n) * 8;
#pragma unroll
    for (int j = 0; j < 8; ++j) op[j] = col[j];
}

// ---------------------------------------------------------------------------
// K3: per chain, fold the 64 chunk matrices into logZ via log-semiring
// mat-vec on an 8-vector starting at 0.
// ---------------------------------------------------------------------------
__global__ __launch_bounds__(256) void k3_combine(
    const float* __restrict__ cmat, float* __restrict__ corr)
{
    const int tid = threadIdx.x;
    const int d   = tid & 7;
    const int n   = blockIdx.x * 32 + (tid >> 3);

    float v[8];
#pragma unroll
    for (int j = 0; j < 8; ++j) v[j] = 0.0f;

#pragma unroll 1
    for (int g = 0; g < NCHUNK; ++g) {
        const float* mg = cmat + ((size_t)g * 8 * N_DIM + n) * 8 + d;
        float mm[8];
#pragma unroll
        for (int j = 0; j < 8; ++j) mm[j] = mg[(size_t)j * N_DIM * 8];
        float tv[8];
#pragma unroll
        for (int j = 0; j < 8; ++j) tv[j] = mm[j] + v[j];
        float m = tv[0];
#pragma unroll
        for (int j = 1; j < 8; ++j) m = fmaxf(m, tv[j]);
        float ss = 0.0f;
#pragma unroll
        for (int j = 0; j < 8; ++j) ss += fexp2(tv[j] - m);
        const float nv = m + flog2(ss);
#pragma unroll
        for (int j = 0; j < 8; ++j) v[j] = __shfl(nv, j, 8);
    }
    float m = v[0];
#pragma unroll
    for (int j = 1; j < 8; ++j) m = fmaxf(m, v[j]);
    float ss = 0.0f;
#pragma unroll
    for (int j = 0; j < 8; ++j) ss += fexp2(v[j] - m);
    const float lz2 = m + flog2(ss);                 // base-2 logZ
    if (d == 0) corr[n] = lz2 * LN2_F / (float)T_DIM;
}

// ---------------------------------------------------------------------------
// K4: out[t][n][c] = y[t][n][c] - corr[n]
// ---------------------------------------------------------------------------
__global__ __launch_bounds__(256) void k4_final(
    float* __restrict__ out, const float* __restrict__ corr)
{
    const unsigned int i = blockIdx.x * 256u + threadIdx.x;  // float4 index
    float4* o4 = (float4*)out;
    float4 v = o4[i];
    const unsigned int n = (i / 10u) & (N_DIM - 1);          // 10 float4 / row
    const float cr = corr[n];
    v.x -= cr; v.y -= cr; v.z -= cr; v.w -= cr;
    o4[i] = v;
}

// ---------------------------------------------------------------------------
extern "C" void kernel_launch(void* const* d_in, const int* in_sizes, int n_in,
                              void* d_out, int out_size, void* d_ws, size_t ws_size,
                              hipStream_t stream)
{
    const float* x = (const float*)d_in[0];
    const float* W = (const float*)d_in[1];
    const float* b = (const float*)d_in[2];
    float* y = (float*)d_out;

    float* cmat = (float*)d_ws;                               // 64*8*256*8 f32 = 4 MB
    float* corr = (float*)d_ws + (size_t)NCHUNK * 8 * N_DIM * 8;

    hipLaunchKernelGGL(k1_gemm_tanh, dim3(1024), dim3(256), 0, stream, x, W, b, y);
    hipLaunchKernelGGL(k2_chunks,    dim3(512),  dim3(256), 0, stream, y, cmat);
    hipLaunchKernelGGL(k3_combine,   dim3(8),    dim3(256), 0, stream, cmat, corr);
    hipLaunchKernelGGL(k4_final,     dim3((T_DIM * N_DIM * C_DIM / 4) / 256),
                       dim3(256), 0, stream, y, corr);
}

// Round 9
// 253.179 us; speedup vs baseline: 1.0450x; 1.0450x over previous
//
#include <hip/hip_runtime.h>
#include <hip/hip_bf16.h>

#define T_DIM 2048
#define N_DIM 256
#define K_DIM 256
#define C_DIM 40
#define CHUNK 32
#define NCHUNK 64                     // T_DIM / CHUNK
#define NSUPER (T_DIM * N_DIM / 64)   // 8192 supertiles of 64 rows

#define LOG2E_F 1.44269504088896340736f
#define LN2_F   0.69314718055994530942f
#define NEGBIG  (-1.0e30f)

typedef short bf16x8 __attribute__((ext_vector_type(8)));
typedef float f32x4  __attribute__((ext_vector_type(4)));

__device__ __forceinline__ float fexp2(float x) { return exp2f(x); }
__device__ __forceinline__ float flog2(float x) { return log2f(x); }
__device__ __forceinline__ float frcp(float x) { return __frcp_rn(x); }

// two fp32 -> one u32 of two bf16 (RNE; compiler emits v_cvt_pk_bf16_f32)
__device__ __forceinline__ unsigned int pk2(float a, float b)
{
    __hip_bfloat162 h = __float22bfloat162_rn(make_float2(a, b));
    unsigned int r;
    __builtin_memcpy(&r, &h, sizeof(r));
    return r;
}

__device__ __forceinline__ uint4 pack8u(float4 lo, float4 hi)
{
    uint4 t;
    t.x = pk2(lo.x, lo.y);
    t.y = pk2(lo.z, lo.w);
    t.z = pk2(hi.x, hi.y);
    t.w = pk2(hi.z, hi.w);
    return t;
}

__device__ __forceinline__ bf16x8 as_bf16x8(uint4 u)
{
    bf16x8 r;
    __builtin_memcpy(&r, &u, sizeof(r));
    return r;
}

__device__ __forceinline__ unsigned short bf16r(float v)
{
    return (unsigned short)(pk2(v, 0.0f) & 0xffffu);
}

// bf16 (as u16 in low/high half of u32) -> exact fp32
__device__ __forceinline__ float bl(unsigned int w) { return __uint_as_float(w << 16); }
__device__ __forceinline__ float bh(unsigned int w) { return __uint_as_float(w & 0xffff0000u); }

__device__ __forceinline__ float tanh5(float v)
{
    const float e = fexp2(fabsf(v) * (2.0f * LOG2E_F)); // e^(2|v|)
    const float t = 1.0f - 2.0f * frcp(e + 1.0f);       // tanh(|v|)
    return 5.0f * copysignf(t, v);
}

// ---------------------------------------------------------------------------
// K1: yb[row][c] = bf16(5*tanh(dot(x[row], W[c]) + b[c]))  via bf16 MFMA.
// Round-8 falsified the per-instruction sector theory; remaining structural
// difference vs the 6.3 TB/s copy ubench is load-stream granularity: the
// MFMA A-layout forces 16 rows x 64 B per instruction. Fix: LDS-stage a
// 64-row tile with FULLY CONTIGUOUS 1KB-per-wave-instruction loads (copy-
// ubench shape), bf16-convert on the fly, XOR-swizzled LDS ((row&7)<<4 ->
// conflict-free ds_read_b128 fragments). 8 waves = 4 M-tiles x 2 K-halves;
// K-half partials combined via a small LDS buffer. W-frags: 12/wave in
// VGPRs (48 VGPR - no R5-style starvation). 2 barriers/tile, 16 waves/CU.
// ---------------------------------------------------------------------------
__global__ __launch_bounds__(512, 4) void k1_gemm_tanh(
    const float* __restrict__ x, const float* __restrict__ W,
    const float* __restrict__ b, unsigned short* __restrict__ yb)
{
    __shared__ __align__(16) unsigned char xl[64 * 512];   // 32 KB bf16 tile (swizzled)
    __shared__ __align__(16) float pl[4 * 12 * 64];        // 12 KB partials [mt][j][lane]

    const int tid  = threadIdx.x;
    const int wave = tid >> 6;
    const int lane = tid & 63;
    const int lr   = lane & 15;
    const int kg   = lane >> 4;
    const int mt   = wave & 3;            // M-tile 0..3 (rows mt*16..+15)
    const int kh   = wave >> 2;           // K-half: ks in [kh*4, kh*4+4)

    const float bc0 = b[lr];
    const float bc1 = b[16 + lr];
    const float bc2 = (lr < 8) ? b[32 + lr] : 0.0f;

    // ---- W fragments for this wave's 4 k-slices (48 VGPR) ----
    bf16x8 wf[4][3];
#pragma unroll
    for (int i = 0; i < 4; ++i) {
        const int ks = kh * 4 + i;
#pragma unroll
        for (int nt = 0; nt < 3; ++nt) {
            const int col = nt * 16 + lr;
            float4 lo = make_float4(0, 0, 0, 0), hi = lo;
            if (col < C_DIM) {
                const float* wp = W + (size_t)col * K_DIM + ks * 32 + kg * 8;
                lo = *(const float4*)wp;
                hi = *(const float4*)(wp + 4);
            }
            wf[i][nt] = as_bf16x8(pack8u(lo, hi));
        }
    }

#pragma unroll 1
    for (int st = blockIdx.x; st < NSUPER; st += gridDim.x) {
        // ---- stage 64 rows x 256 f32 -> bf16 LDS; 1 KB contiguous per
        //      wave-instruction (f4 = p*512+tid => one row per wave) ----
        const float4* __restrict__ xg4 =
            (const float4*)(x + (size_t)st * 64 * K_DIM);
#pragma unroll
        for (int p = 0; p < 8; ++p) {
            const int f4  = p * 512 + tid;   // 0..4095
            const int row = f4 >> 6;
            const int kq  = f4 & 63;
            const float4 v = xg4[f4];
            uint2 w2;
            w2.x = pk2(v.x, v.y);
            w2.y = pk2(v.z, v.w);
            const int off = (row * 512 + kq * 8) ^ ((row & 7) << 4);
            *(uint2*)(xl + off) = w2;
        }
        __syncthreads();   // A: tile staged (also orders prev pl-read before next pl-write)

        // ---- MFMA over this wave's 4 k-slices ----
        f32x4 af0, af1, af2;
        if (kh == 0) {
            af0 = (f32x4){bc0, bc0, bc0, bc0};
            af1 = (f32x4){bc1, bc1, bc1, bc1};
            af2 = (f32x4){bc2, bc2, bc2, bc2};
        } else {
            af0 = (f32x4){0.f, 0.f, 0.f, 0.f}; af1 = af0; af2 = af0;
        }
        const int rbase = (mt * 16 + lr) * 512;
        const int swz   = (lr & 7) << 4;
#pragma unroll
        for (int i = 0; i < 4; ++i) {
            const int ks = kh * 4 + i;
            const bf16x8 a =
                *(const bf16x8*)(xl + ((rbase + ks * 64 + kg * 16) ^ swz));
            af0 = __builtin_amdgcn_mfma_f32_16x16x32_bf16(a, wf[i][0], af0, 0, 0, 0);
            af1 = __builtin_amdgcn_mfma_f32_16x16x32_bf16(a, wf[i][1], af1, 0, 0, 0);
            af2 = __builtin_amdgcn_mfma_f32_16x16x32_bf16(a, wf[i][2], af2, 0, 0, 0);
        }

        if (kh == 1) {      // publish upper-K partials: pl[mt][j][lane]
            float* p = pl + (mt * 12) * 64 + lane;
#pragma unroll
            for (int j = 0; j < 4; ++j) p[j * 64]       = af0[j];
#pragma unroll
            for (int j = 0; j < 4; ++j) p[(4 + j) * 64] = af1[j];
#pragma unroll
            for (int j = 0; j < 4; ++j) p[(8 + j) * 64] = af2[j];
        }
        __syncthreads();   // C: partials visible; all xl reads complete

        if (kh == 0) {     // combine + epilogue; kh1 waves run ahead to stage
            const float* p = pl + (mt * 12) * 64 + lane;
            unsigned short* yr =
                yb + ((size_t)st * 64 + mt * 16 + kg * 4) * C_DIM;
#pragma unroll
            for (int r = 0; r < 4; ++r) {
                yr[r * C_DIM + lr]      = bf16r(tanh5(af0[r] + p[r * 64]));
                yr[r * C_DIM + 16 + lr] = bf16r(tanh5(af1[r] + p[(4 + r) * 64]));
                if (lr < 8)
                    yr[r * C_DIM + 32 + lr] = bf16r(tanh5(af2[r] + p[(8 + r) * 64]));
            }
        }
    }
}

// ---------------------------------------------------------------------------
// K2: per (chain n, chunk g) propagate the 8x8 log-semiring matrix through
// 32 steps; y now bf16 (5 x uint4 loads, shift-unpack). Base-2 domain.
// ---------------------------------------------------------------------------
__global__ __launch_bounds__(256) void k2_chunks(
    const unsigned short* __restrict__ yb, float* __restrict__ cmat)
{
    const int tid  = threadIdx.x;
    const int wave = tid >> 6;
    const int lane = tid & 63;
    const int task = lane >> 3;   // 8 tasks per wave
    const int c    = lane & 7;    // column owned by this lane
    const int g    = blockIdx.x & (NCHUNK - 1);
    const int n    = ((blockIdx.x >> 6) << 5) + (wave << 3) + task;

    float col[8];
#pragma unroll
    for (int j = 0; j < 8; ++j) col[j] = (j == c) ? 0.0f : NEGBIG;

    const unsigned short* __restrict__ yp =
        yb + ((size_t)(g * CHUNK) * N_DIM + (size_t)n) * C_DIM;

#pragma unroll 1
    for (int s = 0; s < CHUNK; ++s) {
        float sc[C_DIM];
        const uint4* p4 = (const uint4*)yp;
#pragma unroll
        for (int q = 0; q < 5; ++q) {
            const uint4 u = p4[q];
            sc[8 * q + 0] = bl(u.x) * LOG2E_F;
            sc[8 * q + 1] = bh(u.x) * LOG2E_F;
            sc[8 * q + 2] = bl(u.y) * LOG2E_F;
            sc[8 * q + 3] = bh(u.y) * LOG2E_F;
            sc[8 * q + 4] = bl(u.z) * LOG2E_F;
            sc[8 * q + 5] = bh(u.z) * LOG2E_F;
            sc[8 * q + 6] = bl(u.w) * LOG2E_F;
            sc[8 * q + 7] = bh(u.w) * LOG2E_F;
        }
        float nc[8];
#pragma unroll
        for (int d = 0; d < 4; ++d) {          // dense rows: lse over 8
            float tv[8];
#pragma unroll
            for (int j = 0; j < 8; ++j) tv[j] = sc[d * 8 + j] + col[j];
            float m = tv[0];
#pragma unroll
            for (int j = 1; j < 8; ++j) m = fmaxf(m, tv[j]);
            float ss = 0.0f;
#pragma unroll
            for (int j = 0; j < 8; ++j) ss += fexp2(tv[j] - m);
            nc[d] = m + flog2(ss);
        }
#pragma unroll
        for (int i = 0; i < 4; ++i) {          // sparse rows: logaddexp of 2
            const float a  = sc[32 + i] + col[i];
            const float bb = sc[36 + i] + col[i + 4];
            const float m  = fmaxf(a, bb);
            const float ss = fexp2(a - m) + fexp2(bb - m);
            nc[4 + i] = m + flog2(ss);
        }
#pragma unroll
        for (int j = 0; j < 8; ++j) col[j] = nc[j];
        yp += (size_t)N_DIM * C_DIM;
    }
    // store M[j][c] at cmat[((g*8 + c)*N_DIM + n)*8 + j]
    float* __restrict__ op = cmat + (((size_t)g * 8 + c) * N_DIM + n) * 8;
#pragma unroll
    for (int j = 0; j < 8; ++j) op[j] = col[j];
}

// ---------------------------------------------------------------------------
// K3: per chain, fold the 64 chunk matrices into logZ.
// ---------------------------------------------------------------------------
__global__ __launch_bounds__(256) void k3_combine(
    const float* __restrict__ cmat, float* __restrict__ corr)
{
    const int tid = threadIdx.x;
    const int d   = tid & 7;
    const int n   = blockIdx.x * 32 + (tid >> 3);

    float v[8];
#pragma unroll
    for (int j = 0; j < 8; ++j) v[j] = 0.0f;

#pragma unroll 1
    for (int g = 0; g < NCHUNK; ++g) {
        const float* mg = cmat + ((size_t)g * 8 * N_DIM + n) * 8 + d;
        float mm[8];
#pragma unroll
        for (int j = 0; j < 8; ++j) mm[j] = mg[(size_t)j * N_DIM * 8];
        float tv[8];
#pragma unroll
        for (int j = 0; j < 8; ++j) tv[j] = mm[j] + v[j];
        float m = tv[0];
#pragma unroll
        for (int j = 1; j < 8; ++j) m = fmaxf(m, tv[j]);
        float ss = 0.0f;
#pragma unroll
        for (int j = 0; j < 8; ++j) ss += fexp2(tv[j] - m);
        const float nv = m + flog2(ss);
#pragma unroll
        for (int j = 0; j < 8; ++j) v[j] = __shfl(nv, j, 8);
    }
    float m = v[0];
#pragma unroll
    for (int j = 1; j < 8; ++j) m = fmaxf(m, v[j]);
    float ss = 0.0f;
#pragma unroll
    for (int j = 0; j < 8; ++j) ss += fexp2(v[j] - m);
    const float lz2 = m + flog2(ss);                 // base-2 logZ
    if (d == 0) corr[n] = lz2 * LN2_F / (float)T_DIM;
}

// ---------------------------------------------------------------------------
// K4: out[t][n][c] = f32(yb[t][n][c]) - corr[n];  8 bf16 per thread (one
// uint4), never crosses a row (40 % 8 == 0).
// ---------------------------------------------------------------------------
__global__ __launch_bounds__(256) void k4_final(
    const unsigned short* __restrict__ yb, const float* __restrict__ corr,
    float* __restrict__ out)
{
    const int i = blockIdx.x * 256 + threadIdx.x;    // 8-elem group index
    const uint4 u = ((const uint4*)yb)[i];
    const float cr = corr[(i / 5) & (N_DIM - 1)];    // 5 groups per row
    float4 o0, o1;
    o0.x = bl(u.x) - cr; o0.y = bh(u.x) - cr;
    o0.z = bl(u.y) - cr; o0.w = bh(u.y) - cr;
    o1.x = bl(u.z) - cr; o1.y = bh(u.z) - cr;
    o1.z = bl(u.w) - cr; o1.w = bh(u.w) - cr;
    float4* o4 = (float4*)out;
    o4[i * 2]     = o0;
    o4[i * 2 + 1] = o1;
}

// ---------------------------------------------------------------------------
extern "C" void kernel_launch(void* const* d_in, const int* in_sizes, int n_in,
                              void* d_out, int out_size, void* d_ws, size_t ws_size,
                              hipStream_t stream)
{
    const float* x = (const float*)d_in[0];
    const float* W = (const float*)d_in[1];
    const float* b = (const float*)d_in[2];
    float* out = (float*)d_out;

    unsigned short* ybf = (unsigned short*)d_ws;              // 40 MB bf16 y
    float* cmat = (float*)((char*)d_ws + (48u << 20));        // 4 MB
    float* corr = cmat + (size_t)NCHUNK * 8 * N_DIM * 8;

    hipLaunchKernelGGL(k1_gemm_tanh, dim3(1024), dim3(512), 0, stream, x, W, b, ybf);
    hipLaunchKernelGGL(k2_chunks,    dim3(512),  dim3(256), 0, stream, ybf, cmat);
    hipLaunchKernelGGL(k3_combine,   dim3(8),    dim3(256), 0, stream, cmat, corr);
    hipLaunchKernelGGL(k4_final,     dim3(T_DIM * N_DIM * C_DIM / 8 / 256),
                       dim3(256), 0, stream, ybf, corr, out);
}